// Round 16
// baseline (1206.171 us; speedup 1.0000x reference)
//
#include <hip/hip_runtime.h>
#include <math.h>

// Decoder forward, MI355X gfx950. Round 16: consolidation of best measured
// configs — qkv/ff1 BM64/BN128 quad (R13 layers, fastest non-logits 1011us),
// logits gemmW plain stores (172us, R12/R14/R15), ff2 split-K atomic,
// attn_out BN64, attn complementary pairing + K/V reg prefetch.
//
// Dims (fixed): V=32000 D=1024 DEPTH=4 H=16 DH=64 FF=4096 B=1 N=2048

#define NSEQ 2048
#define DMODEL 1024
#define NH 16
#define DHEAD 64
#define FFD 4096
#define VOC 32000
#define NLAYER 4

typedef unsigned short u16;
typedef short bf16x8 __attribute__((ext_vector_type(8)));   // 8 bf16 in 4 VGPRs
typedef float f32x4 __attribute__((ext_vector_type(4)));

__device__ __forceinline__ u16 f2bf(float f) {
  unsigned int u = __builtin_bit_cast(unsigned int, f);
  u += 0x7fffu + ((u >> 16) & 1u);   // RNE
  return (u16)(u >> 16);
}

__device__ __forceinline__ void gload16(const void* g, void* l) {
  __builtin_amdgcn_global_load_lds((__attribute__((address_space(1))) void*)g,
                                   (__attribute__((address_space(3))) void*)l,
                                   16, 0, 0);
}

__device__ __forceinline__ f32x4 mfma16x32(bf16x8 a, bf16x8 b, f32x4 c) {
  return __builtin_amdgcn_mfma_f32_16x16x32_bf16(a, b, c, 0, 0, 0);
}

template <int N>
__device__ __forceinline__ void waitvm() {
  if constexpr (N == 0) asm volatile("s_waitcnt vmcnt(0)" ::: "memory");
  else if constexpr (N == 2) asm volatile("s_waitcnt vmcnt(2)" ::: "memory");
  else if constexpr (N == 3) asm volatile("s_waitcnt vmcnt(3)" ::: "memory");
  else if constexpr (N == 4) asm volatile("s_waitcnt vmcnt(4)" ::: "memory");
  else if constexpr (N == 6) asm volatile("s_waitcnt vmcnt(6)" ::: "memory");
  else if constexpr (N == 8) asm volatile("s_waitcnt vmcnt(8)" ::: "memory");
}

// ---------------------------------------------------------------- prep kernels

__global__ __launch_bounds__(256) void k_embed(const int* __restrict__ x,
                                               const float* __restrict__ emb,
                                               float* __restrict__ h) {
  const int n = blockIdx.x, t = threadIdx.x;
  const int tok = x[n];
  reinterpret_cast<float4*>(h + (size_t)n * DMODEL)[t] =
      reinterpret_cast<const float4*>(emb + (size_t)tok * DMODEL)[t];
}

__global__ void k_rope(float* __restrict__ ct, float* __restrict__ st) {
  const int n = blockIdx.x, p = threadIdx.x;  // 32 freq pairs
  const double inv = exp(-(double)(2 * p) / 64.0 * log(10000.0));
  const double a = (double)n * inv;
  ct[n * 32 + p] = (float)cos(a);
  st[n * 32 + p] = (float)sin(a);
}

// f32 [K][Nc] -> bf16 [Nc][K]; 64x64 tiles, float4 reads, ushort4 writes.
__global__ __launch_bounds__(256) void k_transpose(const float* __restrict__ in0,
                                                   u16* __restrict__ out0,
                                                   int K, int Nc,
                                                   size_t ls_in, size_t ls_out) {
  const float* in = in0 + blockIdx.z * ls_in;
  u16* out = out0 + blockIdx.z * ls_out;
  __shared__ float tile[64][65];
  const int kb = blockIdx.x * 64, nb = blockIdx.y * 64;
  const int tr = threadIdx.x >> 4;       // 0..15
  const int tc = threadIdx.x & 15;       // 0..15
#pragma unroll
  for (int r = 0; r < 64; r += 16) {
    const float4 v = *reinterpret_cast<const float4*>(
        &in[(size_t)(kb + r + tr) * Nc + nb + tc * 4]);
    tile[r + tr][tc * 4 + 0] = v.x;
    tile[r + tr][tc * 4 + 1] = v.y;
    tile[r + tr][tc * 4 + 2] = v.z;
    tile[r + tr][tc * 4 + 3] = v.w;
  }
  __syncthreads();
#pragma unroll
  for (int r = 0; r < 64; r += 16) {
    const int n = r + tr;
    ushort4 o;
    o.x = f2bf(tile[tc * 4 + 0][n]);
    o.y = f2bf(tile[tc * 4 + 1][n]);
    o.z = f2bf(tile[tc * 4 + 2][n]);
    o.w = f2bf(tile[tc * 4 + 3][n]);
    *reinterpret_cast<ushort4*>(&out[(size_t)(nb + n) * K + kb + tc * 4]) = o;
  }
}

// rms_norm(h)*gamma -> bf16 (GEMM A input). One row per block (256 thr, float4).
__global__ __launch_bounds__(256) void k_rmsnorm(const float* __restrict__ h,
                                                 const float* __restrict__ gamma,
                                                 u16* __restrict__ out) {
  __shared__ float red[4];
  const int n = blockIdx.x, t = threadIdx.x;
  const float4 v = reinterpret_cast<const float4*>(h + (size_t)n * DMODEL)[t];
  float ss = v.x * v.x + v.y * v.y + v.z * v.z + v.w * v.w;
#pragma unroll
  for (int off = 32; off; off >>= 1) ss += __shfl_down(ss, off);
  if ((t & 63) == 0) red[t >> 6] = ss;
  __syncthreads();
  const float tot = red[0] + red[1] + red[2] + red[3];
  const float inv = 32.0f / fmaxf(sqrtf(tot), 1e-12f);  // sqrt(1024)=32
  const float4 g = reinterpret_cast<const float4*>(gamma)[t];
  ushort4 o;
  o.x = f2bf(v.x * inv * g.x);
  o.y = f2bf(v.y * inv * g.y);
  o.z = f2bf(v.z * inv * g.z);
  o.w = f2bf(v.w * inv * g.w);
  reinterpret_cast<ushort4*>(out + (size_t)n * DMODEL)[t] = o;
}

// ---------------------------------------------------------------- GEMM epilogues
#define EPI_STORE 0
#define EPI_ADD 1
#define EPI_GELU 2
#define EPI_BIAS_ADD 3
#define EPI_QKV 4
#define EPI_ATOM 5

// 64B rows = 4 slots of 16B; 2-level swizzle on SOURCE and READ (both sides).
__device__ __forceinline__ bf16x8 ldsfragT(const char* base, int row, int lg) {
  return *reinterpret_cast<const bf16x8*>(
      base + row * 64 + (((lg ^ (row & 3) ^ ((row >> 2) & 3)) & 3) << 4));
}

// ---------------- k_gemmT: BMxBNxBK32, QUAD-buffer, counted vmcnt ------------
// Tile t staged at iteration t-3 (lead 2 iterations ~1200cyc > HBM latency).
// Boundary waits: t+3<nt: vmcnt(2*SL); t+2<nt: vmcnt(SL); else vmcnt(0).
// SL = BM/64 + BN/64 loads per stage. Staging dest lane-linear tid*16 (m104).
// 4 waves 2x2, wave tile (BM/2)x(BN/2). KSPLIT=2: outer half of the grid
// handles k in [K, 2K) (lda = K*KSPLIT); EPI_ATOM reduces via atomicAdd.
template <int EPI, int BM, int BN, int KSPLIT>
__global__ __launch_bounds__(256) void k_gemmT(
    const u16* __restrict__ A, const u16* __restrict__ BT, int K, int Nc,
    int NMB, const float* __restrict__ bias, const float* __restrict__ add,
    float* __restrict__ outf, u16* __restrict__ outb,
    u16* __restrict__ Qr, u16* __restrict__ Kr, u16* __restrict__ VT,
    const float* __restrict__ ct, const float* __restrict__ st) {
  constexpr int MFR = BM / 32;            // A frags per wave
  constexpr int NFR = BN / 32;            // B frags per wave
  constexpr int ABYTES = BM * 64;         // BM rows x 32 k x 2B
  constexpr int BBYTES = BN * 64;
  constexpr int BUFB = ABYTES + BBYTES;
  constexpr int SL = BM / 64 + BN / 64;   // loads per stage
  __shared__ alignas(16) char sm[4 * BUFB];
  const int nt = K >> 5;
  int bid = blockIdx.x;
  int ksp = 0;
  int inner = gridDim.x;
  if constexpr (KSPLIT == 2) {
    inner = gridDim.x >> 1;
    ksp = bid / inner;
    bid = bid % inner;
  }
  int swz = bid;
  if ((inner & 7) == 0) swz = (swz & 7) * (inner >> 3) + (swz >> 3);
  const int mb = swz % NMB, nb = swz / NMB;  // m-fast: B panel L2-resident
  const int m0 = mb * BM, n0 = nb * BN;
  const int lda = K * KSPLIT;
  const size_t kofs = (size_t)ksp * K;

  const int tid = threadIdx.x, w = tid >> 6, lane = tid & 63;
  const int wr = w >> 1, wc = w & 1;
  const int lr = lane & 15, lg = lane >> 4;

  const int srow = tid >> 2;
  const int gslot = (tid & 3) ^ (srow & 3) ^ ((srow >> 2) & 3);
  const u16* ga0 = A + (size_t)(m0 + srow) * lda + kofs + gslot * 8;
  const u16* ga1 = A + (size_t)(m0 + (BM == 128 ? 64 : 0) + srow) * lda + kofs + gslot * 8;
  const u16* gb0 = BT + (size_t)(n0 + srow) * lda + kofs + gslot * 8;
  const u16* gb1 = BT + (size_t)(n0 + (BN == 128 ? 64 : 0) + srow) * lda + kofs + gslot * 8;
  const int ldOff = tid * 16;             // lane-linear dest (m104)

  auto stage = [&](int b) {
    char* base = sm + b * BUFB;
    gload16(ga0, base + ldOff);
    if constexpr (BM == 128) gload16(ga1, base + 4096 + ldOff);
    gload16(gb0, base + ABYTES + ldOff);
    if constexpr (BN == 128) gload16(gb1, base + ABYTES + 4096 + ldOff);
    ga0 += 32; gb0 += 32;
    if constexpr (BM == 128) ga1 += 32;
    if constexpr (BN == 128) gb1 += 32;
  };

  stage(0);
  stage(1);
  stage(2);
  waitvm<2 * SL>();                        // tile0 landed; 1,2 in flight
  __builtin_amdgcn_s_barrier();

  f32x4 acc[MFR][NFR] = {};
  int cur = 0;
  for (int t = 0; t < nt; ++t) {
    const char* Ab = sm + cur * BUFB;
    const char* Bb = Ab + ABYTES;
    bf16x8 af[MFR], bf[NFR];
#pragma unroll
    for (int i = 0; i < MFR; ++i)
      af[i] = ldsfragT(Ab, wr * (BM / 2) + i * 16 + lr, lg);
#pragma unroll
    for (int i = 0; i < NFR; ++i)
      bf[i] = ldsfragT(Bb, wc * (BN / 2) + i * 16 + lr, lg);
    if (t + 3 < nt) stage((cur + 3) & 3);
    __builtin_amdgcn_s_setprio(1);
#pragma unroll
    for (int mi = 0; mi < MFR; ++mi)
#pragma unroll
      for (int nj = 0; nj < NFR; ++nj)
        acc[mi][nj] = mfma16x32(af[mi], bf[nj], acc[mi][nj]);
    __builtin_amdgcn_s_setprio(0);
    if (t + 1 < nt) {
      __builtin_amdgcn_sched_barrier(0);
      if (t + 3 < nt)      waitvm<2 * SL>();
      else if (t + 2 < nt) waitvm<SL>();
      else                 waitvm<0>();
      __builtin_amdgcn_s_barrier();
      __builtin_amdgcn_sched_barrier(0);
    }
    cur = (cur + 1) & 3;
  }

  if constexpr (EPI == EPI_QKV) {
    // qkv: Nc=3072. Per-element col decode (BN-agnostic):
    // which = col>>10 (0:Q 1:K 2:V), head = (col>>6)&15, d = col&63.
#pragma unroll
    for (int mi = 0; mi < MFR; ++mi) {
#pragma unroll
      for (int nj = 0; nj < NFR; ++nj) {
        const int col = n0 + wc * (BN / 2) + nj * 16 + lr;
        const int which = col >> 10;
        const int hh = (col >> 6) & 15;
        const int d = col & 63;
#pragma unroll
        for (int r = 0; r < 4; ++r) {
          const int row = m0 + wr * (BM / 2) + mi * 16 + lg * 4 + r;
          const float v = acc[mi][nj][r];
          if (which == 2) {
            VT[((size_t)hh * DHEAD + d) * NSEQ + row] = f2bf(v);
          } else {
            const float part = __shfl_xor(v, 1);
            const float sgn = (d & 1) ? 1.0f : -1.0f;
            const float c = ct[row * 32 + (d >> 1)];
            const float s_ = st[row * 32 + (d >> 1)];
            const u16 o = f2bf(v * c + sgn * part * s_);
            u16* dst = (which == 0) ? Qr : Kr;
            dst[((size_t)hh * NSEQ + row) * DHEAD + d] = o;
          }
        }
      }
    }
    return;
  }
#pragma unroll
  for (int mi = 0; mi < MFR; ++mi) {
#pragma unroll
    for (int nj = 0; nj < NFR; ++nj) {
      const int col = n0 + wc * (BN / 2) + nj * 16 + lr;
#pragma unroll
      for (int r = 0; r < 4; ++r) {
        const int row = m0 + wr * (BM / 2) + mi * 16 + lg * 4 + r;
        const size_t idx = (size_t)row * Nc + col;
        float v = acc[mi][nj][r];
        if (EPI == EPI_ATOM) {
          if (ksp == 0) v += bias[col];
          atomicAdd(&outf[idx], v);
        } else if (EPI == EPI_GELU) {
          v += bias[col];
          v = 0.5f * v * (1.0f + erff(v * 0.70710678118654752f));
          outb[idx] = f2bf(v);
        } else if (EPI == EPI_ADD) {
          outf[idx] = v + add[idx];
        } else if (EPI == EPI_BIAS_ADD) {
          outf[idx] = v + bias[col] + add[idx];
        } else {
          outf[idx] = v;
        }
      }
    }
  }
}

// ---------------- k_gemmW: 128x256xBK32, wave tile 64x128 (R12 exact) --------
// Tri-buffer 72KB (2 blk/CU); best measured logits kernel (172us).
template <int EPI>
__global__ __launch_bounds__(256, 2) void k_gemmW(
    const u16* __restrict__ A, const u16* __restrict__ BT, int K, int Nc,
    const float* __restrict__ bias, float* __restrict__ outf,
    u16* __restrict__ outb) {
  constexpr int ABYTES = 8192;            // 128 rows x 32 k x 2B
  constexpr int BUFB = ABYTES + 16384;    // + 256 rows B
  __shared__ alignas(16) char sm[3 * BUFB];
  const int nt = K >> 5;
  const int NMB = 16;
  const int nwg = gridDim.x;
  int swz = blockIdx.x;
  if ((nwg & 7) == 0) swz = (swz & 7) * (nwg >> 3) + (swz >> 3);
  const int mb = swz % NMB, nb = swz / NMB;
  const int m0 = mb * 128, n0 = nb * 256;

  const int tid = threadIdx.x, w = tid >> 6, lane = tid & 63;
  const int wr = w >> 1, wc = w & 1;      // wave tile 64 x 128
  const int lr = lane & 15, lg = lane >> 4;

  const int srow = tid >> 2;
  const int gslot = (tid & 3) ^ (srow & 3) ^ ((srow >> 2) & 3);
  const u16* ga0 = A + (size_t)(m0 + srow) * K + gslot * 8;
  const u16* ga1 = A + (size_t)(m0 + 64 + srow) * K + gslot * 8;
  const u16* gb0 = BT + (size_t)(n0 + srow) * K + gslot * 8;
  const u16* gb1 = BT + (size_t)(n0 + 64 + srow) * K + gslot * 8;
  const u16* gb2 = BT + (size_t)(n0 + 128 + srow) * K + gslot * 8;
  const u16* gb3 = BT + (size_t)(n0 + 192 + srow) * K + gslot * 8;
  const int ldOff = tid * 16;

  auto stage = [&](int b) {
    char* base = sm + b * BUFB;
    gload16(ga0, base + ldOff);
    gload16(ga1, base + 4096 + ldOff);
    gload16(gb0, base + ABYTES + ldOff);
    gload16(gb1, base + ABYTES + 4096 + ldOff);
    gload16(gb2, base + ABYTES + 8192 + ldOff);
    gload16(gb3, base + ABYTES + 12288 + ldOff);
    ga0 += 32; ga1 += 32; gb0 += 32; gb1 += 32; gb2 += 32; gb3 += 32;
  };

  stage(0);
  stage(1);
  waitvm<6>();
  __builtin_amdgcn_s_barrier();

  f32x4 acc[4][8] = {};
  int cur = 0, nx2 = 2;
  for (int t = 0; t < nt; ++t) {
    const char* Ab = sm + cur * BUFB;
    const char* Bb = Ab + ABYTES;
    const bool pf = (t + 2 < nt);
    bf16x8 af[4], bf[8];
#pragma unroll
    for (int i = 0; i < 4; ++i)
      af[i] = ldsfragT(Ab, wr * 64 + i * 16 + lr, lg);
#pragma unroll
    for (int i = 0; i < 8; ++i)
      bf[i] = ldsfragT(Bb, wc * 128 + i * 16 + lr, lg);
    if (pf) stage(nx2);
    __builtin_amdgcn_s_setprio(1);
#pragma unroll
    for (int mi = 0; mi < 4; ++mi)
#pragma unroll
      for (int nj = 0; nj < 8; ++nj)
        acc[mi][nj] = mfma16x32(af[mi], bf[nj], acc[mi][nj]);
    __builtin_amdgcn_s_setprio(0);
    if (t + 1 < nt) {
      __builtin_amdgcn_sched_barrier(0);
      if (pf) waitvm<6>();
      else    waitvm<0>();
      __builtin_amdgcn_s_barrier();
      __builtin_amdgcn_sched_barrier(0);
    }
    cur = (cur == 2) ? 0 : cur + 1;
    nx2 = (nx2 == 2) ? 0 : nx2 + 1;
  }

#pragma unroll
  for (int mi = 0; mi < 4; ++mi) {
#pragma unroll
    for (int nj = 0; nj < 8; ++nj) {
      const int col = n0 + wc * 128 + nj * 16 + lr;
#pragma unroll
      for (int r = 0; r < 4; ++r) {
        const int row = m0 + wr * 64 + mi * 16 + lg * 4 + r;
        const size_t idx = (size_t)row * Nc + col;
        float v = acc[mi][nj][r];
        if (EPI == EPI_GELU) {
          v += bias[col];
          v = 0.5f * v * (1.0f + erff(v * 0.70710678118654752f));
          outb[idx] = f2bf(v);
        } else {
          outf[idx] = v;
        }
      }
    }
  }
}

// ---------------------------------------------------------------- attention
// 512 blocks; id and id+256 (same CU under round-robin) get COMPLEMENTARY
// causal weights (qb, 31-qb) -> uniform per-CU work. Next-iteration K/V
// register prefetch hides L2 latency.
__global__ __launch_bounds__(256) void k_attn(const u16* __restrict__ Qr,
                                              const u16* __restrict__ Kr,
                                              const u16* __restrict__ VT,
                                              u16* __restrict__ O) {
  __shared__ alignas(16) u16 Pl[4][16 * 32];
  const int id = blockIdx.x;
  int qb, hh;
  if (id < 256) { qb = id & 31; hh = id >> 5; }
  else          { qb = 31 - (id & 31); hh = 8 + ((id - 256) >> 5); }
  const int w = threadIdx.x >> 6, lane = threadIdx.x & 63;
  const int lr = lane & 15, lg = lane >> 4;
  const int q0 = qb * 64 + w * 16;
  const u16* Qh = Qr + (size_t)hh * NSEQ * DHEAD;
  const u16* Kh = Kr + (size_t)hh * NSEQ * DHEAD;
  const u16* Vh = VT + (size_t)hh * DHEAD * NSEQ;
  u16* Pw = Pl[w];

  const bf16x8 aq0 = *reinterpret_cast<const bf16x8*>(Qh + (q0 + lr) * DHEAD + lg * 8);
  const bf16x8 aq1 = *reinterpret_cast<const bf16x8*>(Qh + (q0 + lr) * DHEAD + 32 + lg * 8);

  f32x4 o0 = {}, o1 = {}, o2 = {}, o3 = {};
  float m[4], l[4];
#pragma unroll
  for (int r = 0; r < 4; ++r) { m[r] = -1e30f; l[r] = 0.0f; }

  const int jend = q0 + 15;

  auto loadK = [&](int j0, bf16x8* bk) {
    bk[0] = *reinterpret_cast<const bf16x8*>(Kh + (j0 + lr) * DHEAD + lg * 8);
    bk[1] = *reinterpret_cast<const bf16x8*>(Kh + (j0 + lr) * DHEAD + 32 + lg * 8);
    bk[2] = *reinterpret_cast<const bf16x8*>(Kh + (j0 + 16 + lr) * DHEAD + lg * 8);
    bk[3] = *reinterpret_cast<const bf16x8*>(Kh + (j0 + 16 + lr) * DHEAD + 32 + lg * 8);
  };
  auto loadV = [&](int j0, bf16x8* vv) {
    const u16* vb = Vh + j0 + lg * 8;
    vv[0] = *reinterpret_cast<const bf16x8*>(vb + (0 + lr) * NSEQ);
    vv[1] = *reinterpret_cast<const bf16x8*>(vb + (16 + lr) * NSEQ);
    vv[2] = *reinterpret_cast<const bf16x8*>(vb + (32 + lr) * NSEQ);
    vv[3] = *reinterpret_cast<const bf16x8*>(vb + (48 + lr) * NSEQ);
  };

  bf16x8 bk[4], vv[4], bkN[4], vvN[4];
  loadK(0, bk);
  loadV(0, vv);

  for (int j0 = 0; j0 <= jend; j0 += 32) {
    if (j0 + 32 <= jend) { loadK(j0 + 32, bkN); loadV(j0 + 32, vvN); }

    f32x4 s0 = {}, s1 = {};
    s0 = mfma16x32(aq0, bk[0], s0);
    s0 = mfma16x32(aq1, bk[1], s0);
    s1 = mfma16x32(aq0, bk[2], s1);
    s1 = mfma16x32(aq1, bk[3], s1);

    float sv0[4], sv1[4], pm[4];
#pragma unroll
    for (int r = 0; r < 4; ++r) {
      const int irow = q0 + lg * 4 + r;
      sv0[r] = (j0 + lr > irow) ? -1e30f : s0[r] * 0.125f;
      sv1[r] = (j0 + 16 + lr > irow) ? -1e30f : s1[r] * 0.125f;
      pm[r] = fmaxf(sv0[r], sv1[r]);
    }
#pragma unroll
    for (int off = 1; off < 16; off <<= 1)
#pragma unroll
      for (int r = 0; r < 4; ++r) pm[r] = fmaxf(pm[r], __shfl_xor(pm[r], off));
    float p0[4], p1[4], rs[4];
    f32x4 fv;
#pragma unroll
    for (int r = 0; r < 4; ++r) {
      const float mn = fmaxf(m[r], pm[r]);
      fv[r] = __expf(m[r] - mn);
      m[r] = mn;
      p0[r] = __expf(sv0[r] - mn);
      p1[r] = __expf(sv1[r] - mn);
      rs[r] = p0[r] + p1[r];
    }
#pragma unroll
    for (int off = 1; off < 16; off <<= 1)
#pragma unroll
      for (int r = 0; r < 4; ++r) rs[r] += __shfl_xor(rs[r], off);
#pragma unroll
    for (int r = 0; r < 4; ++r) l[r] = l[r] * fv[r] + rs[r];
    o0 *= fv; o1 *= fv; o2 *= fv; o3 *= fv;

#pragma unroll
    for (int r = 0; r < 4; ++r) {
      Pw[(lg * 4 + r) * 32 + lr] = f2bf(p0[r]);
      Pw[(lg * 4 + r) * 32 + 16 + lr] = f2bf(p1[r]);
    }
    const bf16x8 pa = *reinterpret_cast<const bf16x8*>(Pw + lr * 32 + lg * 8);
    o0 = mfma16x32(pa, vv[0], o0);
    o1 = mfma16x32(pa, vv[1], o1);
    o2 = mfma16x32(pa, vv[2], o2);
    o3 = mfma16x32(pa, vv[3], o3);

#pragma unroll
    for (int i = 0; i < 4; ++i) { bk[i] = bkN[i]; vv[i] = vvN[i]; }
  }

#pragma unroll
  for (int r = 0; r < 4; ++r) {
    const int row = q0 + lg * 4 + r;
    const float invl = 1.0f / l[r];
    u16* orow = O + (size_t)row * DMODEL + hh * DHEAD;
    orow[0 * 16 + lr] = f2bf(o0[r] * invl);
    orow[1 * 16 + lr] = f2bf(o1[r] * invl);
    orow[2 * 16 + lr] = f2bf(o2[r] * invl);
    orow[3 * 16 + lr] = f2bf(o3[r] * invl);
  }
}

// ---------------------------------------------------------------- launch

extern "C" void kernel_launch(void* const* d_in, const int* in_sizes, int n_in,
                              void* d_out, int out_size, void* d_ws, size_t ws_size,
                              hipStream_t stream) {
  (void)in_sizes; (void)n_in;
  const int* x = (const int*)d_in[0];
  const float* emb = (const float*)d_in[1];
  const float* attn_gamma = (const float*)d_in[2];
  const float* w_qkv = (const float*)d_in[3];
  const float* w_attn_out = (const float*)d_in[4];
  const float* ff_gamma = (const float*)d_in[5];
  const float* w_ff1 = (const float*)d_in[6];
  const float* b_ff1 = (const float*)d_in[7];
  const float* w_ff2 = (const float*)d_in[8];
  const float* b_ff2 = (const float*)d_in[9];
  const float* final_gamma = (const float*)d_in[10];
  const float* w_logits = (const float*)d_in[11];
  float* out = (float*)d_out;

  const size_t EARLY_NEED = 176ull << 20;
  const size_t FINAL_NEED = 72ull << 20;
  char* earlyBase;
  char* finalBase;
  if (ws_size >= EARLY_NEED + FINAL_NEED) {
    earlyBase = (char*)d_ws;
    finalBase = (char*)d_ws + EARLY_NEED;
  } else if (ws_size >= FINAL_NEED && (size_t)out_size * 4 >= EARLY_NEED) {
    earlyBase = (char*)d_out;
    finalBase = (char*)d_ws;
  } else {
    return;
  }
  size_t eoff = 0, foff = 0;
  auto ealloc = [&](size_t b) { void* p = earlyBase + eoff; eoff += (b + 255) & ~(size_t)255; return p; };
  auto falloc = [&](size_t b) { void* p = finalBase + foff; foff += (b + 255) & ~(size_t)255; return p; };

  u16* wqkvT = (u16*)ealloc((size_t)NLAYER * 3072 * DMODEL * 2);
  u16* wattnT = (u16*)ealloc((size_t)NLAYER * DMODEL * DMODEL * 2);
  u16* wff1T = (u16*)ealloc((size_t)NLAYER * FFD * DMODEL * 2);
  u16* wff2T = (u16*)ealloc((size_t)NLAYER * DMODEL * FFD * 2);
  float* h = (float*)ealloc((size_t)NSEQ * DMODEL * 4);
  u16* Qr = (u16*)ealloc((size_t)NH * NSEQ * DHEAD * 2);
  u16* Kr = (u16*)ealloc((size_t)NH * NSEQ * DHEAD * 2);
  u16* VTb = (u16*)ealloc((size_t)NH * NSEQ * DHEAD * 2);
  u16* Ob = (u16*)ealloc((size_t)NSEQ * DMODEL * 2);
  u16* ff1b = (u16*)ealloc((size_t)NSEQ * FFD * 2);
  float* ct = (float*)ealloc((size_t)NSEQ * 32 * 4);
  float* st = (float*)ealloc((size_t)NSEQ * 32 * 4);
  u16* wlogT = (u16*)falloc((size_t)VOC * DMODEL * 2);
  u16* xn = (u16*)falloc((size_t)NSEQ * DMODEL * 2);

  k_rope<<<dim3(NSEQ), dim3(32), 0, stream>>>(ct, st);
  k_transpose<<<dim3(16, 48, NLAYER), 256, 0, stream>>>(
      w_qkv, wqkvT, DMODEL, 3072, (size_t)DMODEL * 3072, (size_t)3072 * DMODEL);
  k_transpose<<<dim3(16, 16, NLAYER), 256, 0, stream>>>(
      w_attn_out, wattnT, DMODEL, DMODEL, (size_t)DMODEL * DMODEL, (size_t)DMODEL * DMODEL);
  k_transpose<<<dim3(16, 64, NLAYER), 256, 0, stream>>>(
      w_ff1, wff1T, DMODEL, FFD, (size_t)DMODEL * FFD, (size_t)FFD * DMODEL);
  k_transpose<<<dim3(64, 16, NLAYER), 256, 0, stream>>>(
      w_ff2, wff2T, FFD, DMODEL, (size_t)FFD * DMODEL, (size_t)DMODEL * FFD);
  k_transpose<<<dim3(16, 500, 1), 256, 0, stream>>>(
      w_logits, wlogT, DMODEL, VOC, 0, 0);

  k_embed<<<dim3(NSEQ), 256, 0, stream>>>(x, emb, h);

  for (int lyr = 0; lyr < NLAYER; ++lyr) {
    k_rmsnorm<<<dim3(NSEQ), 256, 0, stream>>>(h, attn_gamma + (size_t)lyr * DMODEL, xn);
    k_gemmT<EPI_QKV, 64, 128, 1><<<dim3(32 * 24), 256, 0, stream>>>(
        xn, wqkvT + (size_t)lyr * 3072 * DMODEL, DMODEL, 3072, 32,
        nullptr, nullptr, nullptr, nullptr, Qr, Kr, VTb, ct, st);
    k_attn<<<dim3(512), 256, 0, stream>>>(Qr, Kr, VTb, Ob);
    k_gemmT<EPI_ADD, 64, 64, 1><<<dim3(32 * 16), 256, 0, stream>>>(
        Ob, wattnT + (size_t)lyr * DMODEL * DMODEL, DMODEL, DMODEL, 32,
        nullptr, h, h, nullptr, nullptr, nullptr, nullptr, nullptr, nullptr);
    k_rmsnorm<<<dim3(NSEQ), 256, 0, stream>>>(h, ff_gamma + (size_t)lyr * DMODEL, xn);
    k_gemmT<EPI_GELU, 64, 128, 1><<<dim3(32 * 32), 256, 0, stream>>>(
        xn, wff1T + (size_t)lyr * FFD * DMODEL, DMODEL, FFD, 32,
        b_ff1 + (size_t)lyr * FFD, nullptr, nullptr, ff1b,
        nullptr, nullptr, nullptr, nullptr, nullptr);
    // ff2 split-K=2: each half does K=2048 (lda=4096); reduction via
    // atomicAdd into h (h already holds the residual; ks=0 adds bias).
    k_gemmT<EPI_ATOM, 64, 64, 2><<<dim3(32 * 16 * 2), 256, 0, stream>>>(
        ff1b, wff2T + (size_t)lyr * DMODEL * FFD, FFD / 2, DMODEL, 32,
        b_ff2 + (size_t)lyr * DMODEL, nullptr, h, nullptr,
        nullptr, nullptr, nullptr, nullptr, nullptr);
  }

  k_rmsnorm<<<dim3(NSEQ), 256, 0, stream>>>(h, final_gamma, xn);
  k_gemmW<EPI_STORE><<<dim3(16 * 125), 256, 0, stream>>>(
      xn, wlogT, DMODEL, VOC, nullptr, out, nullptr);
}

// Round 17
// 1198.740 us; speedup vs baseline: 1.0062x; 1.0062x over previous
//
#include <hip/hip_runtime.h>
#include <math.h>

// Decoder forward, MI355X gfx950. Round 17: cherry-pick of best measured
// pieces — nt-stores on TRANSPOSE only (coalesced, keeps 233MB weight stream
// out of L2; R13-verified), plain stores on logits (R16-verified 172us),
// rope merged into embed. Layer kernels identical to R13/R16.
//
// Dims (fixed): V=32000 D=1024 DEPTH=4 H=16 DH=64 FF=4096 B=1 N=2048

#define NSEQ 2048
#define DMODEL 1024
#define NH 16
#define DHEAD 64
#define FFD 4096
#define VOC 32000
#define NLAYER 4

typedef unsigned short u16;
typedef short bf16x8 __attribute__((ext_vector_type(8)));   // 8 bf16 in 4 VGPRs
typedef float f32x4 __attribute__((ext_vector_type(4)));

__device__ __forceinline__ u16 f2bf(float f) {
  unsigned int u = __builtin_bit_cast(unsigned int, f);
  u += 0x7fffu + ((u >> 16) & 1u);   // RNE
  return (u16)(u >> 16);
}

__device__ __forceinline__ void gload16(const void* g, void* l) {
  __builtin_amdgcn_global_load_lds((__attribute__((address_space(1))) void*)g,
                                   (__attribute__((address_space(3))) void*)l,
                                   16, 0, 0);
}

__device__ __forceinline__ f32x4 mfma16x32(bf16x8 a, bf16x8 b, f32x4 c) {
  return __builtin_amdgcn_mfma_f32_16x16x32_bf16(a, b, c, 0, 0, 0);
}

template <int N>
__device__ __forceinline__ void waitvm() {
  if constexpr (N == 0) asm volatile("s_waitcnt vmcnt(0)" ::: "memory");
  else if constexpr (N == 2) asm volatile("s_waitcnt vmcnt(2)" ::: "memory");
  else if constexpr (N == 3) asm volatile("s_waitcnt vmcnt(3)" ::: "memory");
  else if constexpr (N == 4) asm volatile("s_waitcnt vmcnt(4)" ::: "memory");
  else if constexpr (N == 6) asm volatile("s_waitcnt vmcnt(6)" ::: "memory");
  else if constexpr (N == 8) asm volatile("s_waitcnt vmcnt(8)" ::: "memory");
}

// ---------------------------------------------------------------- prep kernels

// embed + rope table fused: 2048 blocks; all 256 threads copy the token row,
// threads 0..31 additionally compute the row's cos/sin pairs.
__global__ __launch_bounds__(256) void k_embed(const int* __restrict__ x,
                                               const float* __restrict__ emb,
                                               float* __restrict__ h,
                                               float* __restrict__ ct,
                                               float* __restrict__ st) {
  const int n = blockIdx.x, t = threadIdx.x;
  const int tok = x[n];
  reinterpret_cast<float4*>(h + (size_t)n * DMODEL)[t] =
      reinterpret_cast<const float4*>(emb + (size_t)tok * DMODEL)[t];
  if (t < 32) {
    const double inv = exp(-(double)(2 * t) / 64.0 * log(10000.0));
    const double a = (double)n * inv;
    ct[n * 32 + t] = (float)cos(a);
    st[n * 32 + t] = (float)sin(a);
  }
}

// f32 [K][Nc] -> bf16 [Nc][K]; 64x64 tiles, float4 reads. NONTEMPORAL ushort4
// writes: fully coalesced rows (no partial-line RMW) + keeps the 233MB weight
// stream out of L2 during prep (R13-measured faster).
__global__ __launch_bounds__(256) void k_transpose(const float* __restrict__ in0,
                                                   u16* __restrict__ out0,
                                                   int K, int Nc,
                                                   size_t ls_in, size_t ls_out) {
  const float* in = in0 + blockIdx.z * ls_in;
  u16* out = out0 + blockIdx.z * ls_out;
  __shared__ float tile[64][65];
  const int kb = blockIdx.x * 64, nb = blockIdx.y * 64;
  const int tr = threadIdx.x >> 4;       // 0..15
  const int tc = threadIdx.x & 15;       // 0..15
#pragma unroll
  for (int r = 0; r < 64; r += 16) {
    const float4 v = *reinterpret_cast<const float4*>(
        &in[(size_t)(kb + r + tr) * Nc + nb + tc * 4]);
    tile[r + tr][tc * 4 + 0] = v.x;
    tile[r + tr][tc * 4 + 1] = v.y;
    tile[r + tr][tc * 4 + 2] = v.z;
    tile[r + tr][tc * 4 + 3] = v.w;
  }
  __syncthreads();
#pragma unroll
  for (int r = 0; r < 64; r += 16) {
    const int n = r + tr;
    ushort4 o;
    o.x = f2bf(tile[tc * 4 + 0][n]);
    o.y = f2bf(tile[tc * 4 + 1][n]);
    o.z = f2bf(tile[tc * 4 + 2][n]);
    o.w = f2bf(tile[tc * 4 + 3][n]);
    const unsigned long long ull = __builtin_bit_cast(unsigned long long, o);
    __builtin_nontemporal_store(
        ull, reinterpret_cast<unsigned long long*>(
                 &out[(size_t)(nb + n) * K + kb + tc * 4]));
  }
}

// rms_norm(h)*gamma -> bf16 (GEMM A input). One row per block (256 thr, float4).
__global__ __launch_bounds__(256) void k_rmsnorm(const float* __restrict__ h,
                                                 const float* __restrict__ gamma,
                                                 u16* __restrict__ out) {
  __shared__ float red[4];
  const int n = blockIdx.x, t = threadIdx.x;
  const float4 v = reinterpret_cast<const float4*>(h + (size_t)n * DMODEL)[t];
  float ss = v.x * v.x + v.y * v.y + v.z * v.z + v.w * v.w;
#pragma unroll
  for (int off = 32; off; off >>= 1) ss += __shfl_down(ss, off);
  if ((t & 63) == 0) red[t >> 6] = ss;
  __syncthreads();
  const float tot = red[0] + red[1] + red[2] + red[3];
  const float inv = 32.0f / fmaxf(sqrtf(tot), 1e-12f);  // sqrt(1024)=32
  const float4 g = reinterpret_cast<const float4*>(gamma)[t];
  ushort4 o;
  o.x = f2bf(v.x * inv * g.x);
  o.y = f2bf(v.y * inv * g.y);
  o.z = f2bf(v.z * inv * g.z);
  o.w = f2bf(v.w * inv * g.w);
  reinterpret_cast<ushort4*>(out + (size_t)n * DMODEL)[t] = o;
}

// ---------------------------------------------------------------- GEMM epilogues
#define EPI_STORE 0
#define EPI_ADD 1
#define EPI_GELU 2
#define EPI_BIAS_ADD 3
#define EPI_QKV 4
#define EPI_ATOM 5

// 64B rows = 4 slots of 16B; 2-level swizzle on SOURCE and READ (both sides).
__device__ __forceinline__ bf16x8 ldsfragT(const char* base, int row, int lg) {
  return *reinterpret_cast<const bf16x8*>(
      base + row * 64 + (((lg ^ (row & 3) ^ ((row >> 2) & 3)) & 3) << 4));
}

// ---------------- k_gemmT: BMxBNxBK32, QUAD-buffer, counted vmcnt ------------
// Tile t staged at iteration t-3 (lead 2 iterations ~1200cyc > HBM latency).
// Boundary waits: t+3<nt: vmcnt(2*SL); t+2<nt: vmcnt(SL); else vmcnt(0).
// SL = BM/64 + BN/64 loads per stage. Staging dest lane-linear tid*16 (m104).
// 4 waves 2x2, wave tile (BM/2)x(BN/2). KSPLIT=2: outer half of the grid
// handles k in [K, 2K) (lda = K*KSPLIT); EPI_ATOM reduces via atomicAdd.
template <int EPI, int BM, int BN, int KSPLIT>
__global__ __launch_bounds__(256) void k_gemmT(
    const u16* __restrict__ A, const u16* __restrict__ BT, int K, int Nc,
    int NMB, const float* __restrict__ bias, const float* __restrict__ add,
    float* __restrict__ outf, u16* __restrict__ outb,
    u16* __restrict__ Qr, u16* __restrict__ Kr, u16* __restrict__ VT,
    const float* __restrict__ ct, const float* __restrict__ st) {
  constexpr int MFR = BM / 32;            // A frags per wave
  constexpr int NFR = BN / 32;            // B frags per wave
  constexpr int ABYTES = BM * 64;         // BM rows x 32 k x 2B
  constexpr int BBYTES = BN * 64;
  constexpr int BUFB = ABYTES + BBYTES;
  constexpr int SL = BM / 64 + BN / 64;   // loads per stage
  __shared__ alignas(16) char sm[4 * BUFB];
  const int nt = K >> 5;
  int bid = blockIdx.x;
  int ksp = 0;
  int inner = gridDim.x;
  if constexpr (KSPLIT == 2) {
    inner = gridDim.x >> 1;
    ksp = bid / inner;
    bid = bid % inner;
  }
  int swz = bid;
  if ((inner & 7) == 0) swz = (swz & 7) * (inner >> 3) + (swz >> 3);
  const int mb = swz % NMB, nb = swz / NMB;  // m-fast: B panel L2-resident
  const int m0 = mb * BM, n0 = nb * BN;
  const int lda = K * KSPLIT;
  const size_t kofs = (size_t)ksp * K;

  const int tid = threadIdx.x, w = tid >> 6, lane = tid & 63;
  const int wr = w >> 1, wc = w & 1;
  const int lr = lane & 15, lg = lane >> 4;

  const int srow = tid >> 2;
  const int gslot = (tid & 3) ^ (srow & 3) ^ ((srow >> 2) & 3);
  const u16* ga0 = A + (size_t)(m0 + srow) * lda + kofs + gslot * 8;
  const u16* ga1 = A + (size_t)(m0 + (BM == 128 ? 64 : 0) + srow) * lda + kofs + gslot * 8;
  const u16* gb0 = BT + (size_t)(n0 + srow) * lda + kofs + gslot * 8;
  const u16* gb1 = BT + (size_t)(n0 + (BN == 128 ? 64 : 0) + srow) * lda + kofs + gslot * 8;
  const int ldOff = tid * 16;             // lane-linear dest (m104)

  auto stage = [&](int b) {
    char* base = sm + b * BUFB;
    gload16(ga0, base + ldOff);
    if constexpr (BM == 128) gload16(ga1, base + 4096 + ldOff);
    gload16(gb0, base + ABYTES + ldOff);
    if constexpr (BN == 128) gload16(gb1, base + ABYTES + 4096 + ldOff);
    ga0 += 32; gb0 += 32;
    if constexpr (BM == 128) ga1 += 32;
    if constexpr (BN == 128) gb1 += 32;
  };

  stage(0);
  stage(1);
  stage(2);
  waitvm<2 * SL>();                        // tile0 landed; 1,2 in flight
  __builtin_amdgcn_s_barrier();

  f32x4 acc[MFR][NFR] = {};
  int cur = 0;
  for (int t = 0; t < nt; ++t) {
    const char* Ab = sm + cur * BUFB;
    const char* Bb = Ab + ABYTES;
    bf16x8 af[MFR], bf[NFR];
#pragma unroll
    for (int i = 0; i < MFR; ++i)
      af[i] = ldsfragT(Ab, wr * (BM / 2) + i * 16 + lr, lg);
#pragma unroll
    for (int i = 0; i < NFR; ++i)
      bf[i] = ldsfragT(Bb, wc * (BN / 2) + i * 16 + lr, lg);
    if (t + 3 < nt) stage((cur + 3) & 3);
    __builtin_amdgcn_s_setprio(1);
#pragma unroll
    for (int mi = 0; mi < MFR; ++mi)
#pragma unroll
      for (int nj = 0; nj < NFR; ++nj)
        acc[mi][nj] = mfma16x32(af[mi], bf[nj], acc[mi][nj]);
    __builtin_amdgcn_s_setprio(0);
    if (t + 1 < nt) {
      __builtin_amdgcn_sched_barrier(0);
      if (t + 3 < nt)      waitvm<2 * SL>();
      else if (t + 2 < nt) waitvm<SL>();
      else                 waitvm<0>();
      __builtin_amdgcn_s_barrier();
      __builtin_amdgcn_sched_barrier(0);
    }
    cur = (cur + 1) & 3;
  }

  if constexpr (EPI == EPI_QKV) {
    // qkv: Nc=3072. Per-element col decode (BN-agnostic):
    // which = col>>10 (0:Q 1:K 2:V), head = (col>>6)&15, d = col&63.
#pragma unroll
    for (int mi = 0; mi < MFR; ++mi) {
#pragma unroll
      for (int nj = 0; nj < NFR; ++nj) {
        const int col = n0 + wc * (BN / 2) + nj * 16 + lr;
        const int which = col >> 10;
        const int hh = (col >> 6) & 15;
        const int d = col & 63;
#pragma unroll
        for (int r = 0; r < 4; ++r) {
          const int row = m0 + wr * (BM / 2) + mi * 16 + lg * 4 + r;
          const float v = acc[mi][nj][r];
          if (which == 2) {
            VT[((size_t)hh * DHEAD + d) * NSEQ + row] = f2bf(v);
          } else {
            const float part = __shfl_xor(v, 1);
            const float sgn = (d & 1) ? 1.0f : -1.0f;
            const float c = ct[row * 32 + (d >> 1)];
            const float s_ = st[row * 32 + (d >> 1)];
            const u16 o = f2bf(v * c + sgn * part * s_);
            u16* dst = (which == 0) ? Qr : Kr;
            dst[((size_t)hh * NSEQ + row) * DHEAD + d] = o;
          }
        }
      }
    }
    return;
  }
#pragma unroll
  for (int mi = 0; mi < MFR; ++mi) {
#pragma unroll
    for (int nj = 0; nj < NFR; ++nj) {
      const int col = n0 + wc * (BN / 2) + nj * 16 + lr;
#pragma unroll
      for (int r = 0; r < 4; ++r) {
        const int row = m0 + wr * (BM / 2) + mi * 16 + lg * 4 + r;
        const size_t idx = (size_t)row * Nc + col;
        float v = acc[mi][nj][r];
        if (EPI == EPI_ATOM) {
          if (ksp == 0) v += bias[col];
          atomicAdd(&outf[idx], v);
        } else if (EPI == EPI_GELU) {
          v += bias[col];
          v = 0.5f * v * (1.0f + erff(v * 0.70710678118654752f));
          outb[idx] = f2bf(v);
        } else if (EPI == EPI_ADD) {
          outf[idx] = v + add[idx];
        } else if (EPI == EPI_BIAS_ADD) {
          outf[idx] = v + bias[col] + add[idx];
        } else {
          outf[idx] = v;
        }
      }
    }
  }
}

// ---------------- k_gemmW: 128x256xBK32, wave tile 64x128 (R12 exact) --------
// Tri-buffer 72KB (2 blk/CU); best measured logits kernel (172us). Plain
// stores (nt-store caused partial-line HBM RMW on this scattered epilogue).
template <int EPI>
__global__ __launch_bounds__(256, 2) void k_gemmW(
    const u16* __restrict__ A, const u16* __restrict__ BT, int K, int Nc,
    const float* __restrict__ bias, float* __restrict__ outf,
    u16* __restrict__ outb) {
  constexpr int ABYTES = 8192;            // 128 rows x 32 k x 2B
  constexpr int BUFB = ABYTES + 16384;    // + 256 rows B
  __shared__ alignas(16) char sm[3 * BUFB];
  const int nt = K >> 5;
  const int NMB = 16;
  const int nwg = gridDim.x;
  int swz = blockIdx.x;
  if ((nwg & 7) == 0) swz = (swz & 7) * (nwg >> 3) + (swz >> 3);
  const int mb = swz % NMB, nb = swz / NMB;
  const int m0 = mb * 128, n0 = nb * 256;

  const int tid = threadIdx.x, w = tid >> 6, lane = tid & 63;
  const int wr = w >> 1, wc = w & 1;      // wave tile 64 x 128
  const int lr = lane & 15, lg = lane >> 4;

  const int srow = tid >> 2;
  const int gslot = (tid & 3) ^ (srow & 3) ^ ((srow >> 2) & 3);
  const u16* ga0 = A + (size_t)(m0 + srow) * K + gslot * 8;
  const u16* ga1 = A + (size_t)(m0 + 64 + srow) * K + gslot * 8;
  const u16* gb0 = BT + (size_t)(n0 + srow) * K + gslot * 8;
  const u16* gb1 = BT + (size_t)(n0 + 64 + srow) * K + gslot * 8;
  const u16* gb2 = BT + (size_t)(n0 + 128 + srow) * K + gslot * 8;
  const u16* gb3 = BT + (size_t)(n0 + 192 + srow) * K + gslot * 8;
  const int ldOff = tid * 16;

  auto stage = [&](int b) {
    char* base = sm + b * BUFB;
    gload16(ga0, base + ldOff);
    gload16(ga1, base + 4096 + ldOff);
    gload16(gb0, base + ABYTES + ldOff);
    gload16(gb1, base + ABYTES + 4096 + ldOff);
    gload16(gb2, base + ABYTES + 8192 + ldOff);
    gload16(gb3, base + ABYTES + 12288 + ldOff);
    ga0 += 32; ga1 += 32; gb0 += 32; gb1 += 32; gb2 += 32; gb3 += 32;
  };

  stage(0);
  stage(1);
  waitvm<6>();
  __builtin_amdgcn_s_barrier();

  f32x4 acc[4][8] = {};
  int cur = 0, nx2 = 2;
  for (int t = 0; t < nt; ++t) {
    const char* Ab = sm + cur * BUFB;
    const char* Bb = Ab + ABYTES;
    const bool pf = (t + 2 < nt);
    bf16x8 af[4], bf[8];
#pragma unroll
    for (int i = 0; i < 4; ++i)
      af[i] = ldsfragT(Ab, wr * 64 + i * 16 + lr, lg);
#pragma unroll
    for (int i = 0; i < 8; ++i)
      bf[i] = ldsfragT(Bb, wc * 128 + i * 16 + lr, lg);
    if (pf) stage(nx2);
    __builtin_amdgcn_s_setprio(1);
#pragma unroll
    for (int mi = 0; mi < 4; ++mi)
#pragma unroll
      for (int nj = 0; nj < 8; ++nj)
        acc[mi][nj] = mfma16x32(af[mi], bf[nj], acc[mi][nj]);
    __builtin_amdgcn_s_setprio(0);
    if (t + 1 < nt) {
      __builtin_amdgcn_sched_barrier(0);
      if (pf) waitvm<6>();
      else    waitvm<0>();
      __builtin_amdgcn_s_barrier();
      __builtin_amdgcn_sched_barrier(0);
    }
    cur = (cur == 2) ? 0 : cur + 1;
    nx2 = (nx2 == 2) ? 0 : nx2 + 1;
  }

#pragma unroll
  for (int mi = 0; mi < 4; ++mi) {
#pragma unroll
    for (int nj = 0; nj < 8; ++nj) {
      const int col = n0 + wc * 128 + nj * 16 + lr;
#pragma unroll
      for (int r = 0; r < 4; ++r) {
        const int row = m0 + wr * 64 + mi * 16 + lg * 4 + r;
        const size_t idx = (size_t)row * Nc + col;
        float v = acc[mi][nj][r];
        if (EPI == EPI_GELU) {
          v += bias[col];
          v = 0.5f * v * (1.0f + erff(v * 0.70710678118654752f));
          outb[idx] = f2bf(v);
        } else {
          outf[idx] = v;
        }
      }
    }
  }
}

// ---------------------------------------------------------------- attention
// 512 blocks; id and id+256 (same CU under round-robin) get COMPLEMENTARY
// causal weights (qb, 31-qb) -> uniform per-CU work. Next-iteration K/V
// register prefetch hides L2 latency.
__global__ __launch_bounds__(256) void k_attn(const u16* __restrict__ Qr,
                                              const u16* __restrict__ Kr,
                                              const u16* __restrict__ VT,
                                              u16* __restrict__ O) {
  __shared__ alignas(16) u16 Pl[4][16 * 32];
  const int id = blockIdx.x;
  int qb, hh;
  if (id < 256) { qb = id & 31; hh = id >> 5; }
  else          { qb = 31 - (id & 31); hh = 8 + ((id - 256) >> 5); }
  const int w = threadIdx.x >> 6, lane = threadIdx.x & 63;
  const int lr = lane & 15, lg = lane >> 4;
  const int q0 = qb * 64 + w * 16;
  const u16* Qh = Qr + (size_t)hh * NSEQ * DHEAD;
  const u16* Kh = Kr + (size_t)hh * NSEQ * DHEAD;
  const u16* Vh = VT + (size_t)hh * DHEAD * NSEQ;
  u16* Pw = Pl[w];

  const bf16x8 aq0 = *reinterpret_cast<const bf16x8*>(Qh + (q0 + lr) * DHEAD + lg * 8);
  const bf16x8 aq1 = *reinterpret_cast<const bf16x8*>(Qh + (q0 + lr) * DHEAD + 32 + lg * 8);

  f32x4 o0 = {}, o1 = {}, o2 = {}, o3 = {};
  float m[4], l[4];
#pragma unroll
  for (int r = 0; r < 4; ++r) { m[r] = -1e30f; l[r] = 0.0f; }

  const int jend = q0 + 15;

  auto loadK = [&](int j0, bf16x8* bk) {
    bk[0] = *reinterpret_cast<const bf16x8*>(Kh + (j0 + lr) * DHEAD + lg * 8);
    bk[1] = *reinterpret_cast<const bf16x8*>(Kh + (j0 + lr) * DHEAD + 32 + lg * 8);
    bk[2] = *reinterpret_cast<const bf16x8*>(Kh + (j0 + 16 + lr) * DHEAD + lg * 8);
    bk[3] = *reinterpret_cast<const bf16x8*>(Kh + (j0 + 16 + lr) * DHEAD + 32 + lg * 8);
  };
  auto loadV = [&](int j0, bf16x8* vv) {
    const u16* vb = Vh + j0 + lg * 8;
    vv[0] = *reinterpret_cast<const bf16x8*>(vb + (0 + lr) * NSEQ);
    vv[1] = *reinterpret_cast<const bf16x8*>(vb + (16 + lr) * NSEQ);
    vv[2] = *reinterpret_cast<const bf16x8*>(vb + (32 + lr) * NSEQ);
    vv[3] = *reinterpret_cast<const bf16x8*>(vb + (48 + lr) * NSEQ);
  };

  bf16x8 bk[4], vv[4], bkN[4], vvN[4];
  loadK(0, bk);
  loadV(0, vv);

  for (int j0 = 0; j0 <= jend; j0 += 32) {
    if (j0 + 32 <= jend) { loadK(j0 + 32, bkN); loadV(j0 + 32, vvN); }

    f32x4 s0 = {}, s1 = {};
    s0 = mfma16x32(aq0, bk[0], s0);
    s0 = mfma16x32(aq1, bk[1], s0);
    s1 = mfma16x32(aq0, bk[2], s1);
    s1 = mfma16x32(aq1, bk[3], s1);

    float sv0[4], sv1[4], pm[4];
#pragma unroll
    for (int r = 0; r < 4; ++r) {
      const int irow = q0 + lg * 4 + r;
      sv0[r] = (j0 + lr > irow) ? -1e30f : s0[r] * 0.125f;
      sv1[r] = (j0 + 16 + lr > irow) ? -1e30f : s1[r] * 0.125f;
      pm[r] = fmaxf(sv0[r], sv1[r]);
    }
#pragma unroll
    for (int off = 1; off < 16; off <<= 1)
#pragma unroll
      for (int r = 0; r < 4; ++r) pm[r] = fmaxf(pm[r], __shfl_xor(pm[r], off));
    float p0[4], p1[4], rs[4];
    f32x4 fv;
#pragma unroll
    for (int r = 0; r < 4; ++r) {
      const float mn = fmaxf(m[r], pm[r]);
      fv[r] = __expf(m[r] - mn);
      m[r] = mn;
      p0[r] = __expf(sv0[r] - mn);
      p1[r] = __expf(sv1[r] - mn);
      rs[r] = p0[r] + p1[r];
    }
#pragma unroll
    for (int off = 1; off < 16; off <<= 1)
#pragma unroll
      for (int r = 0; r < 4; ++r) rs[r] += __shfl_xor(rs[r], off);
#pragma unroll
    for (int r = 0; r < 4; ++r) l[r] = l[r] * fv[r] + rs[r];
    o0 *= fv; o1 *= fv; o2 *= fv; o3 *= fv;

#pragma unroll
    for (int r = 0; r < 4; ++r) {
      Pw[(lg * 4 + r) * 32 + lr] = f2bf(p0[r]);
      Pw[(lg * 4 + r) * 32 + 16 + lr] = f2bf(p1[r]);
    }
    const bf16x8 pa = *reinterpret_cast<const bf16x8*>(Pw + lr * 32 + lg * 8);
    o0 = mfma16x32(pa, vv[0], o0);
    o1 = mfma16x32(pa, vv[1], o1);
    o2 = mfma16x32(pa, vv[2], o2);
    o3 = mfma16x32(pa, vv[3], o3);

#pragma unroll
    for (int i = 0; i < 4; ++i) { bk[i] = bkN[i]; vv[i] = vvN[i]; }
  }

#pragma unroll
  for (int r = 0; r < 4; ++r) {
    const int row = q0 + lg * 4 + r;
    const float invl = 1.0f / l[r];
    u16* orow = O + (size_t)row * DMODEL + hh * DHEAD;
    orow[0 * 16 + lr] = f2bf(o0[r] * invl);
    orow[1 * 16 + lr] = f2bf(o1[r] * invl);
    orow[2 * 16 + lr] = f2bf(o2[r] * invl);
    orow[3 * 16 + lr] = f2bf(o3[r] * invl);
  }
}

// ---------------------------------------------------------------- launch

extern "C" void kernel_launch(void* const* d_in, const int* in_sizes, int n_in,
                              void* d_out, int out_size, void* d_ws, size_t ws_size,
                              hipStream_t stream) {
  (void)in_sizes; (void)n_in;
  const int* x = (const int*)d_in[0];
  const float* emb = (const float*)d_in[1];
  const float* attn_gamma = (const float*)d_in[2];
  const float* w_qkv = (const float*)d_in[3];
  const float* w_attn_out = (const float*)d_in[4];
  const float* ff_gamma = (const float*)d_in[5];
  const float* w_ff1 = (const float*)d_in[6];
  const float* b_ff1 = (const float*)d_in[7];
  const float* w_ff2 = (const float*)d_in[8];
  const float* b_ff2 = (const float*)d_in[9];
  const float* final_gamma = (const float*)d_in[10];
  const float* w_logits = (const float*)d_in[11];
  float* out = (float*)d_out;

  const size_t EARLY_NEED = 176ull << 20;
  const size_t FINAL_NEED = 72ull << 20;
  char* earlyBase;
  char* finalBase;
  if (ws_size >= EARLY_NEED + FINAL_NEED) {
    earlyBase = (char*)d_ws;
    finalBase = (char*)d_ws + EARLY_NEED;
  } else if (ws_size >= FINAL_NEED && (size_t)out_size * 4 >= EARLY_NEED) {
    earlyBase = (char*)d_out;
    finalBase = (char*)d_ws;
  } else {
    return;
  }
  size_t eoff = 0, foff = 0;
  auto ealloc = [&](size_t b) { void* p = earlyBase + eoff; eoff += (b + 255) & ~(size_t)255; return p; };
  auto falloc = [&](size_t b) { void* p = finalBase + foff; foff += (b + 255) & ~(size_t)255; return p; };

  u16* wqkvT = (u16*)ealloc((size_t)NLAYER * 3072 * DMODEL * 2);
  u16* wattnT = (u16*)ealloc((size_t)NLAYER * DMODEL * DMODEL * 2);
  u16* wff1T = (u16*)ealloc((size_t)NLAYER * FFD * DMODEL * 2);
  u16* wff2T = (u16*)ealloc((size_t)NLAYER * DMODEL * FFD * 2);
  float* h = (float*)ealloc((size_t)NSEQ * DMODEL * 4);
  u16* Qr = (u16*)ealloc((size_t)NH * NSEQ * DHEAD * 2);
  u16* Kr = (u16*)ealloc((size_t)NH * NSEQ * DHEAD * 2);
  u16* VTb = (u16*)ealloc((size_t)NH * NSEQ * DHEAD * 2);
  u16* Ob = (u16*)ealloc((size_t)NSEQ * DMODEL * 2);
  u16* ff1b = (u16*)ealloc((size_t)NSEQ * FFD * 2);
  float* ct = (float*)ealloc((size_t)NSEQ * 32 * 4);
  float* st = (float*)ealloc((size_t)NSEQ * 32 * 4);
  u16* wlogT = (u16*)falloc((size_t)VOC * DMODEL * 2);
  u16* xn = (u16*)falloc((size_t)NSEQ * DMODEL * 2);

  k_embed<<<dim3(NSEQ), 256, 0, stream>>>(x, emb, h, ct, st);
  k_transpose<<<dim3(16, 48, NLAYER), 256, 0, stream>>>(
      w_qkv, wqkvT, DMODEL, 3072, (size_t)DMODEL * 3072, (size_t)3072 * DMODEL);
  k_transpose<<<dim3(16, 16, NLAYER), 256, 0, stream>>>(
      w_attn_out, wattnT, DMODEL, DMODEL, (size_t)DMODEL * DMODEL, (size_t)DMODEL * DMODEL);
  k_transpose<<<dim3(16, 64, NLAYER), 256, 0, stream>>>(
      w_ff1, wff1T, DMODEL, FFD, (size_t)DMODEL * FFD, (size_t)FFD * DMODEL);
  k_transpose<<<dim3(64, 16, NLAYER), 256, 0, stream>>>(
      w_ff2, wff2T, FFD, DMODEL, (size_t)FFD * DMODEL, (size_t)DMODEL * FFD);
  k_transpose<<<dim3(16, 500, 1), 256, 0, stream>>>(
      w_logits, wlogT, DMODEL, VOC, 0, 0);

  for (int lyr = 0; lyr < NLAYER; ++lyr) {
    k_rmsnorm<<<dim3(NSEQ), 256, 0, stream>>>(h, attn_gamma + (size_t)lyr * DMODEL, xn);
    k_gemmT<EPI_QKV, 64, 128, 1><<<dim3(32 * 24), 256, 0, stream>>>(
        xn, wqkvT + (size_t)lyr * 3072 * DMODEL, DMODEL, 3072, 32,
        nullptr, nullptr, nullptr, nullptr, Qr, Kr, VTb, ct, st);
    k_attn<<<dim3(512), 256, 0, stream>>>(Qr, Kr, VTb, Ob);
    k_gemmT<EPI_ADD, 64, 64, 1><<<dim3(32 * 16), 256, 0, stream>>>(
        Ob, wattnT + (size_t)lyr * DMODEL * DMODEL, DMODEL, DMODEL, 32,
        nullptr, h, h, nullptr, nullptr, nullptr, nullptr, nullptr, nullptr);
    k_rmsnorm<<<dim3(NSEQ), 256, 0, stream>>>(h, ff_gamma + (size_t)lyr * DMODEL, xn);
    k_gemmT<EPI_GELU, 64, 128, 1><<<dim3(32 * 32), 256, 0, stream>>>(
        xn, wff1T + (size_t)lyr * FFD * DMODEL, DMODEL, FFD, 32,
        b_ff1 + (size_t)lyr * FFD, nullptr, nullptr, ff1b,
        nullptr, nullptr, nullptr, nullptr, nullptr);
    // ff2 split-K=2: each half does K=2048 (lda=4096); reduction via
    // atomicAdd into h (h already holds the residual; ks=0 adds bias).
    k_gemmT<EPI_ATOM, 64, 64, 2><<<dim3(32 * 16 * 2), 256, 0, stream>>>(
        ff1b, wff2T + (size_t)lyr * DMODEL * FFD, FFD / 2, DMODEL, 32,
        b_ff2 + (size_t)lyr * DMODEL, nullptr, h, nullptr,
        nullptr, nullptr, nullptr, nullptr, nullptr);
  }

  k_rmsnorm<<<dim3(NSEQ), 256, 0, stream>>>(h, final_gamma, xn);
  k_gemmW<EPI_STORE><<<dim3(16 * 125), 256, 0, stream>>>(
      xn, wlogT, DMODEL, VOC, nullptr, out, nullptr);
}